// Round 6
// baseline (72.644 us; speedup 1.0000x reference)
//
#include <hip/hip_runtime.h>
#include <hip/hip_cooperative_groups.h>
#include <math.h>

// Reference collapses (softmax over size-1 axis == 1) to:
//   s[b,n] = sum_k x[b,k] * W'[k,n]   (M=256, N=160, K=9216)
//   W'[p*8+j][d*16+i] = W[p][d][i][j]; then squash over 16-groups of n.
// bf16 MFMA path (threshold 1.5e-2 >> bf16 error ~4e-3).
// Single cooperative kernel: gemm partials -> grid.sync -> reduce+squash.
#define M 256
#define N 160
#define K 9216
#define CH 72    // k-chunks
#define KC 128   // k per chunk = 16 p
#define BM 64
#define GRID (4 * CH)  // 288 blocks

using f32x4 = __attribute__((ext_vector_type(4))) float;
using bf16x8 = __attribute__((ext_vector_type(8))) short;

__device__ __forceinline__ ushort f2bf(float f) {
  uint u = __builtin_bit_cast(uint, f);
  u += 0x7FFF + ((u >> 16) & 1);  // RNE
  return (ushort)(u >> 16);
}

__global__ __launch_bounds__(256) void fused(const float* __restrict__ x,
                                             const float* __restrict__ W,
                                             float* __restrict__ part,
                                             float* __restrict__ out) {
  __shared__ ushort Wl[N * KC];   // W chunk, bf16, NATURAL source order
  __shared__ ushort Xl[BM * KC];  // X tile, bf16, [row][k] XOR-swizzled

  const int t = threadIdx.x;
  const int bx = blockIdx.x;
  const int mt = bx & 3;
  const int c = bx >> 2;  // 0..CH-1
  const int m0 = mt * BM;
  const int k0 = c * KC;

  // ---- stage X tile: 64 rows x 128 k (fp32 -> bf16), swizzled ----
  {
    const float* xs = x + (size_t)m0 * K + k0;
#pragma unroll
    for (int q = 0; q < 8; ++q) {
      const int f = t + 256 * q;     // float4 idx < 2048
      const int row = f >> 5;
      const int kq = (f & 31) << 2;
      const float4 v = *(const float4*)(xs + (size_t)row * K + kq);
      ushort4 h = {f2bf(v.x), f2bf(v.y), f2bf(v.z), f2bf(v.w)};
      const int E = (row * KC + kq) ^ ((row & 7) << 3);
      *(ushort4*)&Xl[E] = h;
    }
  }
  // ---- stage W chunk: 20480 f32 -> bf16, source-linear (no transpose!) ----
  // B-frag k-map (k = ks*32+lg*8+j) == 8 contiguous floats W[p][d][i][0..7],
  // so fragments are directly addressable in source order.
  {
    const float* wsp = W + (size_t)(c * 16) * 1280;
#pragma unroll
    for (int q = 0; q < 20; ++q) {
      const int f = t + 256 * q;     // float4 idx < 5120
      const float4 v = *(const float4*)(wsp + 4 * (size_t)f);
      ushort4 h = {f2bf(v.x), f2bf(v.y), f2bf(v.z), f2bf(v.w)};
      *(ushort4*)&Wl[4 * f] = h;
    }
  }
  __syncthreads();

  // ---- MFMA: 4 k-steps x 10 n-tiles ----
  const int w = t >> 6;
  const int l = t & 63;
  const int lr = l & 15;
  const int lg = l >> 4;

  f32x4 acc[10];
#pragma unroll
  for (int nt = 0; nt < 10; ++nt) acc[nt] = {0.f, 0.f, 0.f, 0.f};

#pragma unroll
  for (int ks = 0; ks < 4; ++ks) {
    const int arow = w * 16 + lr;
    const int EA = (arow * KC + ks * 32 + lg * 8) ^ ((arow & 7) << 3);
    const bf16x8 a = *(const bf16x8*)&Xl[EA];
#pragma unroll
    for (int nt = 0; nt < 10; ++nt) {
      // lane (lr,lg), tile nt: B[k=(ks*4+lg)*8+j][n=nt*16+lr]
      //   = W[p0+ks*4+lg][nt][lr][j]  -> source offset, contiguous j
      const int EB = (ks * 4 + lg) * 1280 + nt * 128 + lr * 8;
      const bf16x8 b = *(const bf16x8*)&Wl[EB];
      acc[nt] =
          __builtin_amdgcn_mfma_f32_16x16x32_bf16(a, b, acc[nt], 0, 0, 0);
    }
  }

  // ---- store partials: C row = (lane>>4)*4 + reg, col = lane&15 ----
  {
    float* dst = part + (size_t)c * (M * N);
#pragma unroll
    for (int nt = 0; nt < 10; ++nt)
#pragma unroll
      for (int r = 0; r < 4; ++r) {
        const int row = m0 + w * 16 + lg * 4 + r;
        dst[(size_t)row * N + nt * 16 + lr] = acc[nt][r];
      }
  }

  cooperative_groups::this_grid().sync();

  // ---- phase 2: reduce 72 partials + squash (first 160 blocks) ----
  if (bx < (M * N) / 256) {
    const int o = bx * 256 + t;
    float sum = 0.f;
#pragma unroll 8
    for (int cc = 0; cc < CH; ++cc) sum += part[(size_t)cc * (M * N) + o];
    float s2 = sum * sum;
    s2 += __shfl_xor(s2, 1);
    s2 += __shfl_xor(s2, 2);
    s2 += __shfl_xor(s2, 4);
    s2 += __shfl_xor(s2, 8);
    out[o] = sum * s2 / (1.0f + s2) / sqrtf(s2 + 1e-9f);
  }
}

// ---------- fallback (ws too small): atomic gemm + squash ----------
__global__ __launch_bounds__(256) void gemm_atomic(const float* __restrict__ x,
                                                   const float* __restrict__ W,
                                                   float* __restrict__ outp) {
  __shared__ ushort Wl[N * KC];
  __shared__ ushort Xl[BM * KC];
  const int t = threadIdx.x;
  const int bx = blockIdx.x;
  const int mt = bx & 3;
  const int c = bx >> 2;
  const int m0 = mt * BM;
  const int k0 = c * KC;
  {
    const float* xs = x + (size_t)m0 * K + k0;
#pragma unroll
    for (int q = 0; q < 8; ++q) {
      const int f = t + 256 * q;
      const int row = f >> 5;
      const int kq = (f & 31) << 2;
      const float4 v = *(const float4*)(xs + (size_t)row * K + kq);
      ushort4 h = {f2bf(v.x), f2bf(v.y), f2bf(v.z), f2bf(v.w)};
      const int E = (row * KC + kq) ^ ((row & 7) << 3);
      *(ushort4*)&Xl[E] = h;
    }
  }
  {
    const float* wsp = W + (size_t)(c * 16) * 1280;
#pragma unroll
    for (int q = 0; q < 20; ++q) {
      const int f = t + 256 * q;
      const float4 v = *(const float4*)(wsp + 4 * (size_t)f);
      ushort4 h = {f2bf(v.x), f2bf(v.y), f2bf(v.z), f2bf(v.w)};
      *(ushort4*)&Wl[4 * f] = h;
    }
  }
  __syncthreads();
  const int w = t >> 6;
  const int l = t & 63;
  const int lr = l & 15;
  const int lg = l >> 4;
  f32x4 acc[10];
#pragma unroll
  for (int nt = 0; nt < 10; ++nt) acc[nt] = {0.f, 0.f, 0.f, 0.f};
#pragma unroll
  for (int ks = 0; ks < 4; ++ks) {
    const int arow = w * 16 + lr;
    const int EA = (arow * KC + ks * 32 + lg * 8) ^ ((arow & 7) << 3);
    const bf16x8 a = *(const bf16x8*)&Xl[EA];
#pragma unroll
    for (int nt = 0; nt < 10; ++nt) {
      const int EB = (ks * 4 + lg) * 1280 + nt * 128 + lr * 8;
      const bf16x8 b = *(const bf16x8*)&Wl[EB];
      acc[nt] =
          __builtin_amdgcn_mfma_f32_16x16x32_bf16(a, b, acc[nt], 0, 0, 0);
    }
  }
#pragma unroll
  for (int nt = 0; nt < 10; ++nt)
#pragma unroll
    for (int r = 0; r < 4; ++r) {
      const int row = m0 + w * 16 + lg * 4 + r;
      atomicAdd(&outp[(size_t)row * N + nt * 16 + lr], acc[nt][r]);
    }
}

__global__ __launch_bounds__(256) void squash_k(float* __restrict__ out) {
  const int e = blockIdx.x * 256 + threadIdx.x;
  const float s = out[e];
  float s2 = s * s;
  s2 += __shfl_xor(s2, 1);
  s2 += __shfl_xor(s2, 2);
  s2 += __shfl_xor(s2, 4);
  s2 += __shfl_xor(s2, 8);
  out[e] = s * s2 / (1.0f + s2) / sqrtf(s2 + 1e-9f);
}

extern "C" void kernel_launch(void* const* d_in, const int* in_sizes, int n_in,
                              void* d_out, int out_size, void* d_ws,
                              size_t ws_size, hipStream_t stream) {
  const float* x = (const float*)d_in[0];  // [256,1152,8,1]
  const float* W = (const float*)d_in[1];  // [1152,10,16,8]
  float* out = (float*)d_out;              // [256,10,16,1] = 40960 f32

  const size_t need = (size_t)CH * M * N * sizeof(float);  // 11.8 MB
  if (ws_size >= need) {
    float* part = (float*)d_ws;
    void* args[] = {(void*)&x, (void*)&W, (void*)&part, (void*)&out};
    hipLaunchCooperativeKernel((const void*)fused, dim3(GRID), dim3(256),
                               args, 0, stream);
  } else {
    hipMemsetAsync(out, 0, (size_t)M * N * sizeof(float), stream);
    gemm_atomic<<<GRID, 256, 0, stream>>>(x, W, out);
    squash_k<<<(M * N) / 256, 256, 0, stream>>>(out);
  }
}

// Round 8
// 18.427 us; speedup vs baseline: 3.9423x; 3.9423x over previous
//
#include <hip/hip_runtime.h>
#include <hip/hip_bf16.h>
#include <math.h>

// Reference collapses (softmax over size-1 axis == 1) to:
//   s[b,n] = sum_k x[b,k] * W'[k,n]   (M=256, N=160, K=9216)
//   W'[p*8+j][d*16+i] = W[p][d][i][j]; then squash over 16-groups of n.
// bf16 MFMA path (threshold 1.5e-2 >> bf16 error ~4e-3).
#define M 256
#define N 160
#define K 9216
#define CH 32     // k-chunks
#define KC 288    // k per chunk = 36 p (3 stages of 12 p)
#define BM 32
#define XST 104   // Xl row stride (shorts): 2-way-bank-free, 16B-aligned

using f32x4 = __attribute__((ext_vector_type(4))) float;
using bf16x8 = __attribute__((ext_vector_type(8))) short;

__device__ __forceinline__ ushort f2bf(float f) {
  return __builtin_bit_cast(ushort, __float2bfloat16(f));
}

// grid = 8 m-tiles * 32 chunks = 256 blocks, 256 thr (4 waves).
// Wave w: rows m0+(w&1)*16, n-tiles (w>>1)*5..+4. 45 MFMA/wave.
template <bool ATOMIC>
__global__ __launch_bounds__(256) void gemm_mfma(const float* __restrict__ x,
                                                 const float* __restrict__ W,
                                                 float* __restrict__ part) {
  __shared__ ushort Wl[12 * 1280];   // 12 p, bf16, NATURAL source order
  __shared__ ushort Xl[BM * XST];    // [row][k] bf16, padded stride

  const int t = threadIdx.x;
  const int bx = blockIdx.x;
  const int mt = bx & 7;
  const int c = bx >> 3;             // 0..31
  const int m0 = mt * BM;
  const int k0 = c * KC;

  const int w = t >> 6;
  const int l = t & 63;
  const int lr = l & 15;
  const int lg = l >> 4;
  const int msub = w & 1;
  const int nh = w >> 1;             // n-tile base = nh*5

  float4 wv[15], xv[3];
  // X addressing (per-stage): 768 float4 = 3/thread; row = f/24, kq=(f%24)*4
  int xrow[3], xkq[3];
#pragma unroll
  for (int q = 0; q < 3; ++q) {
    const int f = t + 256 * q;
    xrow[q] = f / 24;
    xkq[q] = (f - xrow[q] * 24) * 4;
  }

  auto load = [&](int s) {
    const float* wsp = W + ((size_t)c * 36 + s * 12) * 1280;
#pragma unroll
    for (int q = 0; q < 15; ++q)
      wv[q] = *(const float4*)(wsp + 4 * (size_t)(t + 256 * q));
    const float* xs = x + (size_t)m0 * K + k0 + s * 96;
#pragma unroll
    for (int q = 0; q < 3; ++q)
      xv[q] = *(const float4*)(xs + (size_t)xrow[q] * K + xkq[q]);
  };
  auto put = [&]() {
#pragma unroll
    for (int q = 0; q < 15; ++q) {
      const int f4 = t + 256 * q;
      ushort4 h = {f2bf(wv[q].x), f2bf(wv[q].y), f2bf(wv[q].z), f2bf(wv[q].w)};
      *(ushort4*)&Wl[4 * f4] = h;
    }
#pragma unroll
    for (int q = 0; q < 3; ++q) {
      ushort4 h = {f2bf(xv[q].x), f2bf(xv[q].y), f2bf(xv[q].z), f2bf(xv[q].w)};
      *(ushort4*)&Xl[xrow[q] * XST + xkq[q]] = h;
    }
  };

  f32x4 acc[5];
#pragma unroll
  for (int nt = 0; nt < 5; ++nt) acc[nt] = {0.f, 0.f, 0.f, 0.f};

  auto comp = [&]() {
#pragma unroll
    for (int ks = 0; ks < 3; ++ks) {
      const bf16x8 a =
          *(const bf16x8*)&Xl[(msub * 16 + lr) * XST + ks * 32 + lg * 8];
#pragma unroll
      for (int nt = 0; nt < 5; ++nt) {
        // B[k=(ks*4+lg)*8+j][n=(nh*5+nt)*16+lr] = W[p][d=nh*5+nt][i=lr][j]
        const bf16x8 b =
            *(const bf16x8*)&Wl[(ks * 4 + lg) * 1280 + (nh * 5 + nt) * 128 +
                                lr * 8];
        acc[nt] =
            __builtin_amdgcn_mfma_f32_16x16x32_bf16(a, b, acc[nt], 0, 0, 0);
      }
    }
  };

  // 3-stage pipeline, reg-prefetch one stage ahead
  load(0);
  put();
  __syncthreads();
  load(1);
  comp();
  __syncthreads();
  put();
  __syncthreads();
  load(2);
  comp();
  __syncthreads();
  put();
  __syncthreads();
  comp();

  // store: C row = (lane>>4)*4 + reg, col = lane&15 (verified R3/R5)
  if (ATOMIC) {
#pragma unroll
    for (int nt = 0; nt < 5; ++nt)
#pragma unroll
      for (int r = 0; r < 4; ++r) {
        const int row = m0 + msub * 16 + lg * 4 + r;
        atomicAdd(&part[(size_t)row * N + (nh * 5 + nt) * 16 + lr],
                  acc[nt][r]);
      }
  } else {
    float* dst = part + (size_t)c * (M * N);
#pragma unroll
    for (int nt = 0; nt < 5; ++nt)
#pragma unroll
      for (int r = 0; r < 4; ++r) {
        const int row = m0 + msub * 16 + lg * 4 + r;
        dst[(size_t)row * N + (nh * 5 + nt) * 16 + lr] = acc[nt][r];
      }
  }
}

// Vectorized reduce (32 chunks) + squash. grid = 160 blocks, 256 thr.
__global__ __launch_bounds__(256) void reduce_squash4(
    const float* __restrict__ part, float* __restrict__ out) {
  __shared__ f32x4 red[256];
  const int t = threadIdx.x;
  const int o4 = t & 63;
  const int slice = t >> 6;          // 0..3, 8 chunks each
  const f32x4* p4 = (const f32x4*)part;
  const int base4 = blockIdx.x * 64;

  f32x4 sum = {0.f, 0.f, 0.f, 0.f};
#pragma unroll
  for (int cc = 0; cc < 8; ++cc) {
    const int c = slice * 8 + cc;
    sum += p4[(size_t)c * (M * N / 4) + base4 + o4];
  }
  red[t] = sum;
  __syncthreads();
  if (t < 64) {
    const f32x4 s = red[t] + red[t + 64] + red[t + 128] + red[t + 192];
    float n2 = s[0] * s[0] + s[1] * s[1] + s[2] * s[2] + s[3] * s[3];
    n2 += __shfl_xor(n2, 1);         // quad = one 16-elem group
    n2 += __shfl_xor(n2, 2);
    const float sc = n2 / (1.0f + n2) / sqrtf(n2 + 1e-9f);
    f32x4 o = {s[0] * sc, s[1] * sc, s[2] * sc, s[3] * sc};
    ((f32x4*)out)[base4 + t] = o;
  }
}

__global__ __launch_bounds__(256) void squash_k(float* __restrict__ out) {
  const int e = blockIdx.x * 256 + threadIdx.x;
  const float s = out[e];
  float s2 = s * s;
  s2 += __shfl_xor(s2, 1);
  s2 += __shfl_xor(s2, 2);
  s2 += __shfl_xor(s2, 4);
  s2 += __shfl_xor(s2, 8);
  out[e] = s * s2 / (1.0f + s2) / sqrtf(s2 + 1e-9f);
}

extern "C" void kernel_launch(void* const* d_in, const int* in_sizes, int n_in,
                              void* d_out, int out_size, void* d_ws,
                              size_t ws_size, hipStream_t stream) {
  const float* x = (const float*)d_in[0];  // [256,1152,8,1]
  const float* W = (const float*)d_in[1];  // [1152,10,16,8]
  float* out = (float*)d_out;              // [256,10,16,1] = 40960 f32

  const size_t need = (size_t)CH * M * N * sizeof(float);  // 5.24 MB
  if (ws_size >= need) {
    gemm_mfma<false><<<256, 256, 0, stream>>>(x, W, (float*)d_ws);
    reduce_squash4<<<(M * N) / 256, 256, 0, stream>>>((const float*)d_ws, out);
  } else {
    hipMemsetAsync(out, 0, (size_t)M * N * sizeof(float), stream);
    gemm_mfma<true><<<256, 256, 0, stream>>>(x, W, out);
    squash_k<<<(M * N) / 256, 256, 0, stream>>>(out);
  }
}